// Round 1
// baseline (1070.369 us; speedup 1.0000x reference)
//
#include <hip/hip_runtime.h>
#include <math.h>

// Problem constants
#define BB 4
#define TT 512
#define FF 257
#define NMIC 4
#define NP 10
#define DM 128
#define C2P 20          // 2*P channels
#define KW 5            // conv taps
#define TP 516          // T padded with 2-row zero halo on each side
#define FP 260          // feat row stride (floats, 16B-multiple)
#define WROW 320        // featT LDS row stride: 16 chunks * 20 words
#define FSTRIDE (2 * TP * FP)   // per-pair advance in feat (2 channels)

// Workspace layout (floats): stats [0,10280) ; wT @10304 (12800) ; feat @23104
// feat = B*20*TP*FP = 10,732,800 floats  -> total ws ~= 43.0 MB required.

// ---------------------------------------------------------------------------
// K0: transpose conv weights once: wT[(p*10 + r)*128 + d] = convw[d][2p+r/5][r%5]
// r = cl*5 + tap, matching k3's featT row order.
// ---------------------------------------------------------------------------
__global__ void k0_wt(const float* __restrict__ convw, float* __restrict__ wT) {
    const int idx = blockIdx.x * 512 + threadIdx.x;
    if (idx >= NP * 10 * DM) return;
    const int p = idx / 1280;
    const int rr = idx - p * 1280;
    const int r = rr >> 7, d = rr & 127;
    const int cl = r / 5, kt = r - cl * 5;
    wT[idx] = convw[(size_t)d * (C2P * KW) + (2 * p + cl) * KW + kt];
}

// ---------------------------------------------------------------------------
// K1: per-(b,f) stats over time: mic means (re,im) and inverse power norm.
// stats layout: [b][f][10]: 0..3 = mean_re[mic], 4..7 = mean_im[mic], 8 = inv_norm
// ---------------------------------------------------------------------------
__global__ __launch_bounds__(256) void k1_stats(const float* __restrict__ x,
                                                float* __restrict__ stats) {
    const int b = blockIdx.x / 65;
    const int ftile = blockIdx.x % 65;
    const int tid = threadIdx.x;
    const int fl = tid & 3;          // f within tile
    const int tt = tid >> 2;         // t-thread 0..63
    const int f = ftile * 4 + fl;

    float sr0 = 0.f, sr1 = 0.f, sr2 = 0.f, sr3 = 0.f;
    float si0 = 0.f, si1 = 0.f, si2 = 0.f, si3 = 0.f;
    float ssq = 0.f;
    if (f < FF) {
        for (int t = tt; t < TT; t += 64) {
            const float* px = x + (((size_t)b * TT + t) * FF + f) * 8;
            float4 v0 = *(const float4*)px;
            float4 v1 = *(const float4*)(px + 4);
            sr0 += v0.x; sr1 += v0.y; sr2 += v0.z; sr3 += v0.w;
            si0 += v1.x; si1 += v1.y; si2 += v1.z; si3 += v1.w;
            ssq += v0.x*v0.x + v0.y*v0.y + v0.z*v0.z + v0.w*v0.w
                 + v1.x*v1.x + v1.y*v1.y + v1.z*v1.z + v1.w*v1.w;
        }
    }
    __shared__ float red[256][10];
    red[tid][0] = sr0; red[tid][1] = sr1; red[tid][2] = sr2; red[tid][3] = sr3;
    red[tid][4] = si0; red[tid][5] = si1; red[tid][6] = si2; red[tid][7] = si3;
    red[tid][8] = ssq;
    __syncthreads();
    for (int s = 32; s >= 1; s >>= 1) {
        if (tt < s) {
            for (int c = 0; c < 9; c++) red[tid][c] += red[tid + 4 * s][c];
        }
        __syncthreads();
    }
    if (tt == 0 && f < FF) {
        const float invT = 1.0f / (float)TT;
        float pw = red[tid][8] * invT;
        float* st = stats + ((size_t)b * FF + f) * 10;
        #pragma unroll
        for (int m = 0; m < 4; m++) {
            float mr = red[tid][m] * invT;
            float mi = red[tid][4 + m] * invT;
            st[m] = mr; st[4 + m] = mi;
            pw -= mr * mr + mi * mi;
        }
        st[8] = rsqrtf(fmaxf(pw, 1e-10f));
    }
}

// ---------------------------------------------------------------------------
// K2: compute SCM features ONCE -> feat[b][ch=2p+ri][tpad][f], tpad = t+2.
// Halo rows tpad in {0,1,514,515} are zero-filled (conv SAME padding).
// Previously k3 recomputed every feature 5x (once per t-block halo).
// ---------------------------------------------------------------------------
__global__ __launch_bounds__(256) void k2_feat(const float* __restrict__ x,
                                               const float* __restrict__ expnt,
                                               const float* __restrict__ ipdf,
                                               const float* __restrict__ stats,
                                               float* __restrict__ feat) {
    const int b = blockIdx.x / TP;
    const int tpad = blockIdx.x % TP;
    const int t = tpad - 2;
    float* fb = feat + ((size_t)b * C2P * TP + tpad) * FP;   // ch stride = TP*FP
    if (t < 0 || t >= TT) {
        for (int idx = threadIdx.x; idx < C2P * FP; idx += 256) {
            const int ch = idx / FP, f = idx - ch * FP;
            fb[(size_t)ch * TP * FP + f] = 0.f;
        }
        return;
    }
    for (int f = threadIdx.x; f < FF; f += 256) {
        const float* px = x + (((size_t)b * TT + t) * FF + f) * 8;
        const float4 v0 = *(const float4*)px;
        const float4 v1 = *(const float4*)(px + 4);
        const float* st = stats + ((size_t)b * FF + f) * 10;
        const float inv = st[8];
        float xr[4], xi[4];
        xr[0] = (v0.x - st[0]) * inv; xr[1] = (v0.y - st[1]) * inv;
        xr[2] = (v0.z - st[2]) * inv; xr[3] = (v0.w - st[3]) * inv;
        xi[0] = (v1.x - st[4]) * inv; xi[1] = (v1.y - st[5]) * inv;
        xi[2] = (v1.z - st[6]) * inv; xi[3] = (v1.w - st[7]) * inv;
        const float sef = 1.0f / (1.0f + __expf(-expnt[f]));
        const float sif = 1.0f / (1.0f + __expf(-ipdf[f]));
        const int MA[NP] = {0,0,0,0,1,1,1,2,2,3};
        const int MB[NP] = {0,1,2,3,1,2,3,2,3,3};
        #pragma unroll
        for (int p = 0; p < NP; p++) {
            const float cra = xr[MA[p]], cia = xi[MA[p]];
            const float crb = xr[MB[p]], cib = xi[MB[p]];
            const float re = cra * crb + cia * cib;
            const float im = cia * crb - cra * cib;
            const float r = sqrtf(re * re + im * im);
            // r^s via hw exp2/log2; r=0 -> -inf -> exp2=0 (matches ref)
            const float bp = exp2f(sef * __log2f(r));
            const float a = r / (bp + 1e-10f);
            const float ang = atan2f(im, re) * sif;
            float sn, cs;
            __sincosf(ang, &sn, &cs);
            fb[(size_t)(2 * p) * TP * FP + f] = a * cs;
            fb[(size_t)(2 * p + 1) * TP * FP + f] = a * sn;
        }
    }
}

// ---------------------------------------------------------------------------
// K3: one block per (b,t). Pure staged GEMM over 10 pairs + fused LayerNorm.
// 512 threads = 32 d-threads (4 d each) x 16 f-threads (17 f each, f=ftid+16j).
// featT LDS layout is chunk-transposed: feature f at word (f&15)*20 + (f>>4),
// so fr loads are 4x ds_read_b128 + 1x b32 (all <=2-way bank = free) instead of
// 17 scalar strided b32 (the old LDS-pipe bottleneck: ~780K cyc/CU).
// Double-buffered reg-staging: issue next pair's global loads before the GEMM,
// ds_write after it -> ONE barrier per pair, HBM latency hidden under FMAs.
// ---------------------------------------------------------------------------
__global__ __launch_bounds__(512, 2) void k3_conv_ln(
        const float* __restrict__ feat,
        const float* __restrict__ wT,
        const float* __restrict__ convb,
        const float* __restrict__ lnw,
        const float* __restrict__ lnb,
        float* __restrict__ out) {
    const int bid = blockIdx.x;
    const int bt = (bid & 7) * 256 + (bid >> 3);  // XCD swizzle: t-adjacent blocks
    const int b = bt >> 9;                        // share feat halo rows in one L2
    const int t = bt & 511;
    const int tid = threadIdx.x;
    const int ftid = tid & 15;
    const int dtid = tid >> 4;      // 0..31
    const int d0 = dtid * 4;

    __shared__ float featT[2][10 * WROW];   // 25.6 KB
    __shared__ float wcs[2][10 * DM];       // 10.2 KB
    __shared__ float wred[16];

    // ---- precompute staging slots (10 rows x 257 feat elems; 1280 weights) ----
    int fsrc[6], fdst[6];
    #pragma unroll
    for (int u = 0; u < 6; u++) {
        const int i = tid + 512 * u;
        fsrc[u] = -1; fdst[u] = 0;
        if (i < 10 * FF) {
            const int r = i / FF, o = i - r * FF;   // r = cl*5 + tap
            const int cl = r / 5, kt = r - cl * 5;
            fsrc[u] = ((b * C2P + cl) * TP + (t + kt)) * FP + o;  // + p*FSTRIDE
            fdst[u] = r * WROW + (o & 15) * 20 + (o >> 4);
        }
    }

    float sv[6], wv[3];
    // ---- prologue: stage pair 0 ----
    #pragma unroll
    for (int u = 0; u < 6; u++) if (fsrc[u] >= 0) sv[u] = feat[fsrc[u]];
    #pragma unroll
    for (int u = 0; u < 3; u++) { const int i = tid + 512 * u; if (i < 1280) wv[u] = wT[i]; }
    #pragma unroll
    for (int u = 0; u < 6; u++) if (fsrc[u] >= 0) featT[0][fdst[u]] = sv[u];
    #pragma unroll
    for (int u = 0; u < 3; u++) { const int i = tid + 512 * u; if (i < 1280) wcs[0][i] = wv[u]; }
    __syncthreads();

    float acc[4][17];
    #pragma unroll
    for (int i = 0; i < 4; i++)
        #pragma unroll
        for (int j = 0; j < 17; j++) acc[i][j] = 0.f;

    int cur = 0;
    for (int p = 0; p < NP; p++) {
        // prefetch pair p+1 into registers (hidden under this pair's GEMM)
        if (p < NP - 1) {
            #pragma unroll
            for (int u = 0; u < 6; u++)
                if (fsrc[u] >= 0) sv[u] = feat[fsrc[u] + (p + 1) * FSTRIDE];
            #pragma unroll
            for (int u = 0; u < 3; u++) {
                const int i = tid + 512 * u;
                if (i < 1280) wv[u] = wT[(p + 1) * 1280 + i];
            }
        }

        const float* fT = featT[cur];
        const float* wc = wcs[cur];
        #pragma unroll
        for (int kk = 0; kk < 10; kk++) {
            const float4 w = *(const float4*)(wc + kk * DM + d0);
            const float* fp_ = fT + kk * WROW + ftid * 20;
            const float4 f0 = *(const float4*)(fp_);
            const float4 f1 = *(const float4*)(fp_ + 4);
            const float4 f2 = *(const float4*)(fp_ + 8);
            const float4 f3 = *(const float4*)(fp_ + 12);
            const float fx = fp_[16];     // j=16 (garbage for ftid>0: masked slot)
            const float wa[4] = {w.x, w.y, w.z, w.w};
            const float fv[17] = {f0.x, f0.y, f0.z, f0.w, f1.x, f1.y, f1.z, f1.w,
                                  f2.x, f2.y, f2.z, f2.w, f3.x, f3.y, f3.z, f3.w, fx};
            #pragma unroll
            for (int i = 0; i < 4; i++)
                #pragma unroll
                for (int j = 0; j < 17; j++)
                    acc[i][j] = fmaf(wa[i], fv[j], acc[i][j]);
        }

        // write next pair into the other buffer; one barrier per pair
        if (p < NP - 1) {
            #pragma unroll
            for (int u = 0; u < 6; u++) if (fsrc[u] >= 0) featT[cur ^ 1][fdst[u]] = sv[u];
            #pragma unroll
            for (int u = 0; u < 3; u++) {
                const int i = tid + 512 * u;
                if (i < 1280) wcs[cur ^ 1][i] = wv[u];
            }
        }
        __syncthreads();
        cur ^= 1;
    }

    // ---- Epilogue: bias + LayerNorm over (d, f<257) then write (coalesced) ----
    float cb[4];
    #pragma unroll
    for (int i = 0; i < 4; i++) cb[i] = convb[d0 + i];

    float s1 = 0.f, s2 = 0.f;
    const int jmax = (ftid == 0) ? 17 : 16;   // f = ftid + 16*j < 257
    #pragma unroll
    for (int i = 0; i < 4; i++) {
        #pragma unroll
        for (int j = 0; j < 17; j++) {
            acc[i][j] += cb[i];
            if (j < jmax) { s1 += acc[i][j]; s2 += acc[i][j] * acc[i][j]; }
        }
    }
    #pragma unroll
    for (int off = 32; off >= 1; off >>= 1) {
        s1 += __shfl_down(s1, off, 64);
        s2 += __shfl_down(s2, off, 64);
    }
    const int wv8 = tid >> 6;                 // 8 waves
    if ((tid & 63) == 0) { wred[wv8] = s1; wred[8 + wv8] = s2; }
    __syncthreads();
    float S1 = 0.f, S2 = 0.f;
    #pragma unroll
    for (int w = 0; w < 8; w++) { S1 += wred[w]; S2 += wred[8 + w]; }
    const float Ninv = 1.0f / (float)(DM * FF);
    const float mu = S1 * Ninv;
    const float var = S2 * Ninv - mu * mu;
    const float rstd = rsqrtf(var + 1e-5f);

    float* op = out + (size_t)bt * DM * FF;
    #pragma unroll
    for (int i = 0; i < 4; i++) {
        const int d = d0 + i;
        #pragma unroll
        for (int j = 0; j < 17; j++) {
            const int f = ftid + 16 * j;
            if (f < FF) {
                const size_t o = (size_t)d * FF + f;
                op[o] = (acc[i][j] - mu) * rstd * lnw[o] + lnb[o];
            }
        }
    }
}

extern "C" void kernel_launch(void* const* d_in, const int* in_sizes, int n_in,
                              void* d_out, int out_size, void* d_ws, size_t ws_size,
                              hipStream_t stream) {
    const float* x     = (const float*)d_in[0];
    const float* expnt = (const float*)d_in[1];
    const float* ipdf  = (const float*)d_in[2];
    const float* convw = (const float*)d_in[3];
    const float* convb = (const float*)d_in[4];
    const float* lnw   = (const float*)d_in[5];
    const float* lnb   = (const float*)d_in[6];
    float* out = (float*)d_out;

    // Workspace: stats 10280 floats; wT 12800 @ 10304; feat 10,732,800 @ 23104.
    // Total ~43.0 MB required.
    float* stats = (float*)d_ws;
    float* wT    = stats + 10304;
    float* feat  = stats + 23104;

    k0_wt<<<25, 512, 0, stream>>>(convw, wT);
    k1_stats<<<BB * 65, 256, 0, stream>>>(x, stats);
    k2_feat<<<BB * TP, 256, 0, stream>>>(x, expnt, ipdf, stats, feat);
    k3_conv_ln<<<BB * TT, 512, 0, stream>>>(feat, wT, convb, lnw, lnb, out);
}